// Round 2
// baseline (8599.288 us; speedup 1.0000x reference)
//
#include <hip/hip_runtime.h>
#include <cstdint>

typedef float f32x4 __attribute__((ext_vector_type(4)));
typedef __bf16 bf16x8 __attribute__((ext_vector_type(8)));
typedef unsigned short us8 __attribute__((ext_vector_type(8)));

#define T2 126

__device__ __forceinline__ unsigned short f2bf(float x){
  union { float f; uint32_t u; } v; v.f = x;
  return (unsigned short)((v.u + 0x7fffu + ((v.u >> 16) & 1u)) >> 16);
}
__device__ __forceinline__ float bf2f(unsigned short h){
  union { uint32_t u; float f; } v; v.u = ((uint32_t)h) << 16; return v.f;
}
__device__ __forceinline__ f32x4 mfma_bf16(us8 a, us8 b, f32x4 c){
  return __builtin_amdgcn_mfma_f32_16x16x32_bf16(
      __builtin_bit_cast(bf16x8, a), __builtin_bit_cast(bf16x8, b), c, 0, 0, 0);
}
__device__ __forceinline__ float sigm(float x){ return 1.0f / (1.0f + __expf(-x)); }

// XOR-swizzled LDS address for a [rows][512] bf16 tile, 8-short chunks.
#define HSWZ(row, chunk) ((row) * 512 + ((((chunk) ^ ((row) & 7))) << 3))

// ---------------------------------------------------------------------------
// Pack a (1536,512) fp32 weight matrix into bf16 MFMA B-operand fragments.
// B = W^T. Tile (jt,kt): lane l elem e holds B[32kt+8*(l>>4)+e][16jt+(l&15)]
//   = W[16jt+(l&15)][32kt+8*(l>>4)+e];  dst[(jt*16+kt)*512 + l*8 + e]
// ---------------------------------------------------------------------------
__global__ void __launch_bounds__(256) pack_w_kernel(const float* __restrict__ w,
                                                     unsigned short* __restrict__ dst){
  int tid = blockIdx.x * 256 + threadIdx.x;     // 0..98303
  int l = tid & 63;
  int tile = tid >> 6;                          // jt*16 + kt
  int kt = tile & 15, jt = tile >> 4;
  int row = jt * 16 + (l & 15);
  int col = kt * 32 + (l >> 4) * 8;
  const float* s = w + (size_t)row * 512 + col;
  unsigned short o[8];
  #pragma unroll
  for (int e = 0; e < 8; e++) o[e] = f2bf(s[e]);
  *(us8*)(dst + (size_t)tid * 8) = *(const us8*)o;
}

// ---------------------------------------------------------------------------
// Patchify conv (4x4 stride 4, ch0=curr frame t+1, ch1=prev frame t) + bias
// + exact GELU -> feat_c bf16, chunk-local sample index n_c = b*Tc + tl.
// ---------------------------------------------------------------------------
__global__ void __launch_bounds__(256) conv_gelu_kernel(const float* __restrict__ frames,
                                                        const float* __restrict__ cw,
                                                        const float* __restrict__ cb,
                                                        unsigned short* __restrict__ feat_c,
                                                        int t0, int Tc){
  __shared__ float im[512];     // [0:256)=prev (t), [256:512)=curr (t+1)
  __shared__ float wl[1024];    // conv_w (o,c,p,q) flat
  int n = blockIdx.x;
  int b = n / Tc, tl = n - b * Tc;
  int t = t0 + tl;
  const float* fr = frames + ((size_t)b * 128 + t) * 256;
  int tid = threadIdx.x;
  ((float2*)im)[tid] = ((const float2*)fr)[tid];   // frames t and t+1 contiguous
  #pragma unroll
  for (int i = 0; i < 4; i++) wl[tid + 256 * i] = cw[tid + 256 * i];
  __syncthreads();
  #pragma unroll
  for (int half = 0; half < 2; half++){
    int oi = tid + half * 256;
    int o = oi >> 4, ii = (oi >> 2) & 3, jj = oi & 3;
    const float* wc = &wl[o * 32];          // [c=0 curr 16][c=1 prev 16]
    float s = cb[o];
    #pragma unroll
    for (int p = 0; p < 4; p++)
      #pragma unroll
      for (int q = 0; q < 4; q++){
        int pix = (ii * 4 + p) * 16 + jj * 4 + q;
        s += im[256 + pix] * wc[p * 4 + q] + im[pix] * wc[16 + p * 4 + q];
      }
    float g = 0.5f * s * (1.0f + erff(s * 0.70710678118654752f));
    feat_c[(size_t)n * 512 + oi] = f2bf(g);
  }
}

// ---------------------------------------------------------------------------
// gates_c = feat_c @ w_ih^T + b_ih -> bf16 (n_c, 1536). M-tile 64, A in LDS
// (XOR-swizzled), B streamed from packed wih_p (L2-resident).
// ---------------------------------------------------------------------------
__global__ void __launch_bounds__(256) gates_gemm_kernel(const unsigned short* __restrict__ feat_c,
                                                         const unsigned short* __restrict__ wih_p,
                                                         const float* __restrict__ b_ih,
                                                         unsigned short* __restrict__ gates_c){
  __shared__ unsigned short alds[64 * 512];
  int tid = threadIdx.x;
  int m0 = blockIdx.x * 64;
  #pragma unroll
  for (int it = 0; it < 16; it++){
    int cid = tid + 256 * it;                 // 0..4095
    int row = cid >> 6, ch = cid & 63;
    uint4 v = *(const uint4*)(feat_c + (size_t)(m0 + row) * 512 + ch * 8);
    *(uint4*)&alds[HSWZ(row, ch)] = v;
  }
  __syncthreads();
  int l = tid & 63, w = tid >> 6;
  int lr = l & 15, lh = l >> 4;
  for (int jg = 0; jg < 6; jg++){
    int jt0 = w * 24 + jg * 4;
    f32x4 acc[4][4];
    #pragma unroll
    for (int mt = 0; mt < 4; mt++)
      #pragma unroll
      for (int jj = 0; jj < 4; jj++) acc[mt][jj] = (f32x4){0.f,0.f,0.f,0.f};
    #pragma unroll
    for (int kt = 0; kt < 16; kt++){
      us8 a[4], bf[4];
      #pragma unroll
      for (int mt = 0; mt < 4; mt++){
        int row = mt * 16 + lr;
        int ch = kt * 4 + lh;
        a[mt] = *(const us8*)&alds[HSWZ(row, ch)];
      }
      #pragma unroll
      for (int jj = 0; jj < 4; jj++)
        bf[jj] = *(const us8*)(wih_p + ((size_t)((jt0 + jj) * 16 + kt) * 512 + l * 8));
      #pragma unroll
      for (int mt = 0; mt < 4; mt++)
        #pragma unroll
        for (int jj = 0; jj < 4; jj++)
          acc[mt][jj] = mfma_bf16(a[mt], bf[jj], acc[mt][jj]);
    }
    #pragma unroll
    for (int jj = 0; jj < 4; jj++){
      int j = (jt0 + jj) * 16 + lr;
      float bias = b_ih[j];
      #pragma unroll
      for (int mt = 0; mt < 4; mt++)
        #pragma unroll
        for (int r = 0; r < 4; r++){
          int m = m0 + mt * 16 + lh * 4 + r;
          gates_c[(size_t)m * 1536 + j] = f2bf(acc[mt][jj][r] + bias);
        }
    }
  }
}

// ---------------------------------------------------------------------------
// GRU scan over one time chunk. 32 blocks x 512 thr (8 waves); block owns
// batch rows [16g, 16g+16). h in LDS bf16 (double-buffered, XOR-swizzled)
// + fp32 per-lane registers. w_hh streamed from packed L2. One barrier/step.
// h carried across chunks via h_state (fp32); first chunk inits h=0.
// ---------------------------------------------------------------------------
__global__ void __launch_bounds__(512) gru_scan_kernel(const unsigned short* __restrict__ gates_c,
                                                       const unsigned short* __restrict__ whh_p,
                                                       const float* __restrict__ b_hh,
                                                       float* __restrict__ h_state,
                                                       unsigned short* __restrict__ outs_c,
                                                       int Tc, int first){
  __shared__ unsigned short hl[2][16 * 512];
  int tid = threadIdx.x;
  int bg = blockIdx.x * 16;
  int l = tid & 63, w = tid >> 6;             // wave 0..7
  int lr = l & 15, lh = l >> 4;
  float bhr[4], bhz[4], bhn[4];
  float hreg[4][4];
  #pragma unroll
  for (int q = 0; q < 4; q++){
    int j = (w * 4 + q) * 16 + lr;
    bhr[q] = b_hh[j]; bhz[q] = b_hh[512 + j]; bhn[q] = b_hh[1024 + j];
  }
  if (first){
    for (int i = tid; i < 16 * 512; i += 512) hl[0][i] = 0;
    #pragma unroll
    for (int q = 0; q < 4; q++)
      #pragma unroll
      for (int r = 0; r < 4; r++) hreg[q][r] = 0.0f;
  } else {
    #pragma unroll
    for (int k = 0; k < 16; k++){
      int i = tid + 512 * k;
      int row = i >> 9, j = i & 511;
      hl[0][HSWZ(row, j >> 3) + (j & 7)] = f2bf(h_state[(size_t)(bg + row) * 512 + j]);
    }
    #pragma unroll
    for (int q = 0; q < 4; q++){
      int j = (w * 4 + q) * 16 + lr;
      #pragma unroll
      for (int r = 0; r < 4; r++)
        hreg[q][r] = h_state[(size_t)(bg + lh * 4 + r) * 512 + j];
    }
  }
  __syncthreads();
  int cur = 0;
  for (int tl = 0; tl < Tc; tl++){
    us8 af[16];
    #pragma unroll
    for (int kt = 0; kt < 16; kt++)
      af[kt] = *(const us8*)&hl[cur][HSWZ(lr, kt * 4 + lh)];
    unsigned short* hn = &hl[cur ^ 1][0];
    #pragma unroll
    for (int q = 0; q < 4; q++){
      int jh = w * 4 + q;                     // hidden tile 0..31
      const unsigned short* bR = whh_p + (size_t)(jh * 16) * 512 + (size_t)l * 8;
      const unsigned short* bZ = bR + (size_t)32 * 16 * 512;
      const unsigned short* bN = bR + (size_t)64 * 16 * 512;
      f32x4 aR = {0.f,0.f,0.f,0.f}, aZ = {0.f,0.f,0.f,0.f}, aN = {0.f,0.f,0.f,0.f};
      #pragma unroll
      for (int kt = 0; kt < 16; kt++){
        aR = mfma_bf16(af[kt], *(const us8*)(bR + kt * 512), aR);
        aZ = mfma_bf16(af[kt], *(const us8*)(bZ + kt * 512), aZ);
        aN = mfma_bf16(af[kt], *(const us8*)(bN + kt * 512), aN);
      }
      int j = jh * 16 + lr;
      #pragma unroll
      for (int r = 0; r < 4; r++){
        int brow = lh * 4 + r;
        size_t gxb = ((size_t)(bg + brow) * Tc + tl) * 1536;
        float gxr = bf2f(gates_c[gxb + j]);
        float gxz = bf2f(gates_c[gxb + 512 + j]);
        float gxn = bf2f(gates_c[gxb + 1024 + j]);
        float rr = sigm(gxr + aR[r] + bhr[q]);
        float zz = sigm(gxz + aZ[r] + bhz[q]);
        float nn = tanhf(gxn + rr * (aN[r] + bhn[q]));
        float hv = (1.0f - zz) * nn + zz * hreg[q][r];
        hreg[q][r] = hv;
        unsigned short hb = f2bf(hv);
        hn[HSWZ(brow, j >> 3) + (j & 7)] = hb;
        outs_c[((size_t)(bg + brow) * Tc + tl) * 512 + j] = hb;
      }
    }
    __syncthreads();
    cur ^= 1;
  }
  // carry h to next chunk
  #pragma unroll
  for (int q = 0; q < 4; q++){
    int j = (w * 4 + q) * 16 + lr;
    #pragma unroll
    for (int r = 0; r < 4; r++)
      h_state[(size_t)(bg + lh * 4 + r) * 512 + j] = hreg[q][r];
  }
}

// ---------------------------------------------------------------------------
// Deconv (4x4 stride 4) + tanh + residual + clip -> fp32 output
// ---------------------------------------------------------------------------
__global__ void __launch_bounds__(256) deconv_kernel(const unsigned short* __restrict__ outs_c,
                                                     const float* __restrict__ dw,
                                                     const float* __restrict__ db,
                                                     const float* __restrict__ frames,
                                                     float* __restrict__ out,
                                                     int t0, int Tc){
  __shared__ float wl[512];
  __shared__ float dv[512];
  int n = blockIdx.x;
  int b = n / Tc, tl = n - b * Tc;
  int t = t0 + tl;
  int tid = threadIdx.x;
  wl[tid] = dw[tid]; wl[tid + 256] = dw[tid + 256];
  dv[tid] = bf2f(outs_c[(size_t)n * 512 + tid]);
  dv[tid + 256] = bf2f(outs_c[(size_t)n * 512 + tid + 256]);
  __syncthreads();
  int row = tid >> 4, col = tid & 15;
  int ii = row >> 2, p = row & 3, jj = col >> 2, q = col & 3;
  float s = db[0];
  #pragma unroll
  for (int c = 0; c < 32; c++)
    s += dv[c * 16 + ii * 4 + jj] * wl[c * 16 + p * 4 + q];
  float d = tanhf(s);
  float cv = frames[((size_t)b * 128 + (t + 1)) * 256 + tid];
  float r = cv + d;
  out[((size_t)b * T2 + t) * 256 + tid] = fminf(fmaxf(r, 0.0f), 1.0f);
}

extern "C" void kernel_launch(void* const* d_in, const int* in_sizes, int n_in,
                              void* d_out, int out_size, void* d_ws, size_t ws_size,
                              hipStream_t stream) {
  const float* frames   = (const float*)d_in[0];
  const float* conv_w   = (const float*)d_in[1];
  const float* conv_b   = (const float*)d_in[2];
  const float* w_ih     = (const float*)d_in[3];
  const float* w_hh     = (const float*)d_in[4];
  const float* b_ih     = (const float*)d_in[5];
  const float* b_hh     = (const float*)d_in[6];
  const float* deconv_w = (const float*)d_in[7];
  const float* deconv_b = (const float*)d_in[8];
  float* out = (float*)d_out;
  char* ws = (char*)d_ws;

  // Pick largest divisor of 126 whose chunked workspace fits ws_size.
  // bytes = 4 MiB fixed (packed weights 2x1.5MB + h_state 1MB)
  //       + Tc * (feat 0.5MB + gates 1.5MB + outs 0.5MB)
  static const int divs[12] = {126, 63, 42, 21, 18, 14, 9, 7, 6, 3, 2, 1};
  int Tc = 1;
  for (int i = 0; i < 12; i++){
    long long need = 4194304LL + 2621440LL * divs[i];
    if (need <= (long long)ws_size){ Tc = divs[i]; break; }
  }
  int G = T2 / Tc;

  unsigned short* wih_p  = (unsigned short*)(ws);
  unsigned short* whh_p  = (unsigned short*)(ws + 1572864LL);
  float*          h_state= (float*)         (ws + 3145728LL);
  unsigned short* feat_c = (unsigned short*)(ws + 4194304LL);
  unsigned short* gates_c= (unsigned short*)(ws + 4194304LL +  524288LL * Tc);
  unsigned short* outs_c = (unsigned short*)(ws + 4194304LL + 2097152LL * Tc);

  pack_w_kernel<<<384, 256, 0, stream>>>(w_ih, wih_p);
  pack_w_kernel<<<384, 256, 0, stream>>>(w_hh, whh_p);

  for (int c = 0; c < G; c++){
    int t0 = c * Tc;
    conv_gelu_kernel<<<512 * Tc, 256, 0, stream>>>(frames, conv_w, conv_b, feat_c, t0, Tc);
    gates_gemm_kernel<<<8 * Tc, 256, 0, stream>>>(feat_c, wih_p, b_ih, gates_c);
    gru_scan_kernel<<<32, 512, 0, stream>>>(gates_c, whh_p, b_hh, h_state, outs_c, Tc, c == 0);
    deconv_kernel<<<512 * Tc, 256, 0, stream>>>(outs_c, deconv_w, deconv_b, frames, out, t0, Tc);
  }
}

// Round 3
// 6779.745 us; speedup vs baseline: 1.2684x; 1.2684x over previous
//
#include <hip/hip_runtime.h>
#include <cstdint>

typedef float f32x4 __attribute__((ext_vector_type(4)));
typedef __bf16 bf16x8 __attribute__((ext_vector_type(8)));
typedef unsigned short us8 __attribute__((ext_vector_type(8)));

#define T2 126

__device__ __forceinline__ unsigned short f2bf(float x){
  union { float f; uint32_t u; } v; v.f = x;
  return (unsigned short)((v.u + 0x7fffu + ((v.u >> 16) & 1u)) >> 16);
}
__device__ __forceinline__ float bf2f(unsigned short h){
  union { uint32_t u; float f; } v; v.u = ((uint32_t)h) << 16; return v.f;
}
__device__ __forceinline__ f32x4 mfma_bf16(us8 a, us8 b, f32x4 c){
  return __builtin_amdgcn_mfma_f32_16x16x32_bf16(
      __builtin_bit_cast(bf16x8, a), __builtin_bit_cast(bf16x8, b), c, 0, 0, 0);
}
__device__ __forceinline__ float sigm(float x){ return 1.0f / (1.0f + __expf(-x)); }

// XOR-swizzled LDS address for a [rows][512] bf16 tile, 8-short chunks.
#define HSWZ(row, chunk) ((row) * 512 + ((((chunk) ^ ((row) & 7))) << 3))

// ---------------------------------------------------------------------------
// Pack (1536,512) fp32 weights -> bf16 MFMA B-fragments.
// Tile (jt,kt): lane l elem e holds W[16jt+(l&15)][32kt+8*(l>>4)+e]
// at dst[(jt*16+kt)*512 + l*8 + e]
// ---------------------------------------------------------------------------
__global__ void __launch_bounds__(256) pack_w_kernel(const float* __restrict__ w,
                                                     unsigned short* __restrict__ dst){
  int tid = blockIdx.x * 256 + threadIdx.x;     // 0..98303
  int l = tid & 63;
  int tile = tid >> 6;                          // jt*16 + kt
  int kt = tile & 15, jt = tile >> 4;
  int row = jt * 16 + (l & 15);
  int col = kt * 32 + (l >> 4) * 8;
  const float* s = w + (size_t)row * 512 + col;
  unsigned short o[8];
  #pragma unroll
  for (int e = 0; e < 8; e++) o[e] = f2bf(s[e]);
  *(us8*)(dst + (size_t)tid * 8) = *(const us8*)o;
}

// ---------------------------------------------------------------------------
// Patchify conv + bias + exact GELU -> feat_c bf16 (chunk-local)
// ---------------------------------------------------------------------------
__global__ void __launch_bounds__(256) conv_gelu_kernel(const float* __restrict__ frames,
                                                        const float* __restrict__ cw,
                                                        const float* __restrict__ cb,
                                                        unsigned short* __restrict__ feat_c,
                                                        int t0, int Tc){
  __shared__ float im[512];
  __shared__ float wl[1024];
  int n = blockIdx.x;
  int b = n / Tc, tl = n - b * Tc;
  int t = t0 + tl;
  const float* fr = frames + ((size_t)b * 128 + t) * 256;
  int tid = threadIdx.x;
  ((float2*)im)[tid] = ((const float2*)fr)[tid];
  #pragma unroll
  for (int i = 0; i < 4; i++) wl[tid + 256 * i] = cw[tid + 256 * i];
  __syncthreads();
  #pragma unroll
  for (int half = 0; half < 2; half++){
    int oi = tid + half * 256;
    int o = oi >> 4, ii = (oi >> 2) & 3, jj = oi & 3;
    const float* wc = &wl[o * 32];
    float s = cb[o];
    #pragma unroll
    for (int p = 0; p < 4; p++)
      #pragma unroll
      for (int q = 0; q < 4; q++){
        int pix = (ii * 4 + p) * 16 + jj * 4 + q;
        s += im[256 + pix] * wc[p * 4 + q] + im[pix] * wc[16 + p * 4 + q];
      }
    float g = 0.5f * s * (1.0f + erff(s * 0.70710678118654752f));
    feat_c[(size_t)n * 512 + oi] = f2bf(g);
  }
}

// ---------------------------------------------------------------------------
// gates_c = feat_c @ w_ih^T + b_ih -> bf16 (n_c, 1536)
// ---------------------------------------------------------------------------
__global__ void __launch_bounds__(256) gates_gemm_kernel(const unsigned short* __restrict__ feat_c,
                                                         const unsigned short* __restrict__ wih_p,
                                                         const float* __restrict__ b_ih,
                                                         unsigned short* __restrict__ gates_c){
  __shared__ unsigned short alds[64 * 512];
  int tid = threadIdx.x;
  int m0 = blockIdx.x * 64;
  #pragma unroll
  for (int it = 0; it < 16; it++){
    int cid = tid + 256 * it;
    int row = cid >> 6, ch = cid & 63;
    uint4 v = *(const uint4*)(feat_c + (size_t)(m0 + row) * 512 + ch * 8);
    *(uint4*)&alds[HSWZ(row, ch)] = v;
  }
  __syncthreads();
  int l = tid & 63, w = tid >> 6;
  int lr = l & 15, lh = l >> 4;
  for (int jg = 0; jg < 6; jg++){
    int jt0 = w * 24 + jg * 4;
    f32x4 acc[4][4];
    #pragma unroll
    for (int mt = 0; mt < 4; mt++)
      #pragma unroll
      for (int jj = 0; jj < 4; jj++) acc[mt][jj] = (f32x4){0.f,0.f,0.f,0.f};
    #pragma unroll
    for (int kt = 0; kt < 16; kt++){
      us8 a[4], bf[4];
      #pragma unroll
      for (int mt = 0; mt < 4; mt++){
        int row = mt * 16 + lr;
        int ch = kt * 4 + lh;
        a[mt] = *(const us8*)&alds[HSWZ(row, ch)];
      }
      #pragma unroll
      for (int jj = 0; jj < 4; jj++)
        bf[jj] = *(const us8*)(wih_p + ((size_t)((jt0 + jj) * 16 + kt) * 512 + l * 8));
      #pragma unroll
      for (int mt = 0; mt < 4; mt++)
        #pragma unroll
        for (int jj = 0; jj < 4; jj++)
          acc[mt][jj] = mfma_bf16(a[mt], bf[jj], acc[mt][jj]);
    }
    #pragma unroll
    for (int jj = 0; jj < 4; jj++){
      int j = (jt0 + jj) * 16 + lr;
      float bias = b_ih[j];
      #pragma unroll
      for (int mt = 0; mt < 4; mt++)
        #pragma unroll
        for (int r = 0; r < 4; r++){
          int m = m0 + mt * 16 + lh * 4 + r;
          gates_c[(size_t)m * 1536 + j] = f2bf(acc[mt][jj][r] + bias);
        }
    }
  }
}

// ---------------------------------------------------------------------------
// Reset flags each scan launch; zero h_glob on the first chunk.
// ---------------------------------------------------------------------------
__global__ void __launch_bounds__(256) scan_init_kernel(unsigned int* __restrict__ flags,
                                                        unsigned short* __restrict__ h_glob,
                                                        int first){
  int tid = blockIdx.x * 256 + threadIdx.x;
  if (tid < 256) flags[tid] = 0;
  if (first){
    for (int i = tid; i < 2 * 512 * 512; i += gridDim.x * 256)
      h_glob[i] = 0;
  }
}

// ---------------------------------------------------------------------------
// Weight-stationary persistent GRU scan.
// Grid = 256 blocks = 16 batch-groups (32 rows) x 16 hidden-slices (32 cols),
// XCD-clustered: blocks of a group land on one XCD (perf heuristic only).
// Per wave (4/block): w_hh fragments for its 16 cols x 3 gates live in 192
// VGPRs for the whole scan (loaded once). Per step: spin on group flags,
// stage h(s) (32x512 bf16) global->LDS, 48 MFMA, lane-local gate math,
// write h(s+1) slice + outs, fence, bump flag. fp32 h in regs; double-
// buffered h_glob; monotone flags => no WAR hazards.
// ---------------------------------------------------------------------------
__global__ void __launch_bounds__(256, 1) gru_scan_kernel(
    const unsigned short* __restrict__ gates_c,
    const unsigned short* __restrict__ whh_p,
    const float* __restrict__ b_hh,
    unsigned short* __restrict__ h_glob,   // [2][512][512] bf16
    float* __restrict__ h_state,           // [512][512] fp32 chunk carry
    unsigned int* __restrict__ flags,      // [16 groups][16 slices]
    unsigned short* __restrict__ outs_c,
    int Tc, int t0){
  __shared__ unsigned short hlds[32 * 512];
  const int tid = threadIdx.x;
  const int B = blockIdx.x;
  const int grp = (B & 7) * 2 + ((B >> 3) >> 4);   // 0..15, same-XCD cluster
  const int slc = (B >> 3) & 15;                   // 0..15
  const int l = tid & 63;
  const int w = tid >> 6;                          // wave 0..3
  const int mt = w & 1, jg = w >> 1;
  const int lr = l & 15, lh = l >> 4;
  const int j = slc * 32 + jg * 16 + lr;           // hidden col
  const int rowbase = grp * 32 + mt * 16 + lh * 4; // + r = batch row

  // persistent weight fragments: gate g tile (jt = g*32 + slc*2 + jg, kt)
  us8 wr[16], wz[16], wn[16];
  {
    const int jtR = slc * 2 + jg;
    #pragma unroll
    for (int kt = 0; kt < 16; kt++){
      wr[kt] = *(const us8*)(whh_p + ((size_t)((jtR      ) * 16 + kt) * 512 + l * 8));
      wz[kt] = *(const us8*)(whh_p + ((size_t)((jtR + 32) * 16 + kt) * 512 + l * 8));
      wn[kt] = *(const us8*)(whh_p + ((size_t)((jtR + 64) * 16 + kt) * 512 + l * 8));
    }
  }
  const float bhr = b_hh[j], bhz = b_hh[512 + j], bhn = b_hh[1024 + j];
  float hprev[4];
  if (t0 == 0){
    hprev[0] = hprev[1] = hprev[2] = hprev[3] = 0.0f;
  } else {
    #pragma unroll
    for (int r = 0; r < 4; r++) hprev[r] = h_state[(size_t)(rowbase + r) * 512 + j];
  }
  unsigned int* gflag = flags + grp * 16;

  for (int tl = 0; tl < Tc; tl++){
    const int s = t0 + tl;
    const unsigned short* hbuf = h_glob + (size_t)(s & 1) * (512 * 512);
    unsigned short* hnext = h_glob + (size_t)((s + 1) & 1) * (512 * 512);
    // prefetch gx for this step (independent of flags -> overlaps the spin)
    float gxr[4], gxz[4], gxn[4];
    #pragma unroll
    for (int r = 0; r < 4; r++){
      size_t gb = ((size_t)(rowbase + r) * Tc + tl) * 1536;
      gxr[r] = bf2f(gates_c[gb + j]);
      gxz[r] = bf2f(gates_c[gb + 512 + j]);
      gxn[r] = bf2f(gates_c[gb + 1024 + j]);
    }
    // wait until every slice of this group has published h(s)
    if (tl > 0){
      if (tid < 16){
        while ((int)__hip_atomic_load(&gflag[tid], __ATOMIC_RELAXED,
                                      __HIP_MEMORY_SCOPE_AGENT) < tl)
          __builtin_amdgcn_s_sleep(1);
      }
      __threadfence();
    }
    __syncthreads();                 // also WAR-protects hlds restage
    // stage h(s) rows [grp*32, grp*32+32) into LDS (XOR-swizzled)
    #pragma unroll
    for (int it = 0; it < 8; it++){
      int cid = tid + 256 * it;
      int row = cid >> 6, ch = cid & 63;
      us8 v = *(const us8*)(hbuf + (size_t)(grp * 32 + row) * 512 + ch * 8);
      *(us8*)&hlds[HSWZ(row, ch)] = v;
    }
    __syncthreads();
    f32x4 aR = {0.f,0.f,0.f,0.f}, aZ = {0.f,0.f,0.f,0.f}, aN = {0.f,0.f,0.f,0.f};
    #pragma unroll
    for (int kt = 0; kt < 16; kt++){
      us8 a = *(const us8*)&hlds[HSWZ(mt * 16 + lr, kt * 4 + lh)];
      aR = mfma_bf16(a, wr[kt], aR);
      aZ = mfma_bf16(a, wz[kt], aZ);
      aN = mfma_bf16(a, wn[kt], aN);
    }
    #pragma unroll
    for (int r = 0; r < 4; r++){
      float rr = sigm(gxr[r] + aR[r] + bhr);
      float zz = sigm(gxz[r] + aZ[r] + bhz);
      float nn = tanhf(gxn[r] + rr * (aN[r] + bhn));
      float hv = (1.0f - zz) * nn + zz * hprev[r];
      hprev[r] = hv;
      unsigned short hb = f2bf(hv);
      hnext[(size_t)(rowbase + r) * 512 + j] = hb;
      outs_c[((size_t)(rowbase + r) * Tc + tl) * 512 + j] = hb;
    }
    __threadfence();                 // own stores globally visible
    __syncthreads();                 // all waves done before publishing
    if (tid == 0)
      __hip_atomic_store(&gflag[slc], (unsigned)(tl + 1), __ATOMIC_RELEASE,
                         __HIP_MEMORY_SCOPE_AGENT);
  }
  // fp32 carry for next chunk
  #pragma unroll
  for (int r = 0; r < 4; r++)
    h_state[(size_t)(rowbase + r) * 512 + j] = hprev[r];
}

// ---------------------------------------------------------------------------
// Deconv + tanh + residual + clip -> fp32 output
// ---------------------------------------------------------------------------
__global__ void __launch_bounds__(256) deconv_kernel(const unsigned short* __restrict__ outs_c,
                                                     const float* __restrict__ dw,
                                                     const float* __restrict__ db,
                                                     const float* __restrict__ frames,
                                                     float* __restrict__ out,
                                                     int t0, int Tc){
  __shared__ float wl[512];
  __shared__ float dv[512];
  int n = blockIdx.x;
  int b = n / Tc, tl = n - b * Tc;
  int t = t0 + tl;
  int tid = threadIdx.x;
  wl[tid] = dw[tid]; wl[tid + 256] = dw[tid + 256];
  dv[tid] = bf2f(outs_c[(size_t)n * 512 + tid]);
  dv[tid + 256] = bf2f(outs_c[(size_t)n * 512 + tid + 256]);
  __syncthreads();
  int row = tid >> 4, col = tid & 15;
  int ii = row >> 2, p = row & 3, jj = col >> 2, q = col & 3;
  float s = db[0];
  #pragma unroll
  for (int c = 0; c < 32; c++)
    s += dv[c * 16 + ii * 4 + jj] * wl[c * 16 + p * 4 + q];
  float d = tanhf(s);
  float cv = frames[((size_t)b * 128 + (t + 1)) * 256 + tid];
  float r = cv + d;
  out[((size_t)b * T2 + t) * 256 + tid] = fminf(fmaxf(r, 0.0f), 1.0f);
}

extern "C" void kernel_launch(void* const* d_in, const int* in_sizes, int n_in,
                              void* d_out, int out_size, void* d_ws, size_t ws_size,
                              hipStream_t stream) {
  const float* frames   = (const float*)d_in[0];
  const float* conv_w   = (const float*)d_in[1];
  const float* conv_b   = (const float*)d_in[2];
  const float* w_ih     = (const float*)d_in[3];
  const float* w_hh     = (const float*)d_in[4];
  const float* b_ih     = (const float*)d_in[5];
  const float* b_hh     = (const float*)d_in[6];
  const float* deconv_w = (const float*)d_in[7];
  const float* deconv_b = (const float*)d_in[8];
  float* out = (float*)d_out;
  char* ws = (char*)d_ws;

  // fixed region: wih_p 1.5M | whh_p 1.5M | h_state 1M | h_glob 1M | flags 4K
  unsigned short* wih_p   = (unsigned short*)(ws);
  unsigned short* whh_p   = (unsigned short*)(ws + 1572864LL);
  float*          h_state = (float*)         (ws + 3145728LL);
  unsigned short* h_glob  = (unsigned short*)(ws + 4194304LL);
  unsigned int*   flags   = (unsigned int*)  (ws + 5242880LL);
  char*           chunkws = ws + 5246976LL;

  // chunked region: feat 0.5M/t + gates 1.5M/t + outs 0.5M/t
  static const int divs[12] = {126, 63, 42, 21, 18, 14, 9, 7, 6, 3, 2, 1};
  int Tc = 1;
  for (int i = 0; i < 12; i++){
    long long need = 5246976LL + 2621440LL * divs[i];
    if (need <= (long long)ws_size){ Tc = divs[i]; break; }
  }
  int G = T2 / Tc;

  unsigned short* feat_c  = (unsigned short*)(chunkws);
  unsigned short* gates_c = (unsigned short*)(chunkws +  524288LL * Tc);
  unsigned short* outs_c  = (unsigned short*)(chunkws + 2097152LL * Tc);

  pack_w_kernel<<<384, 256, 0, stream>>>(w_ih, wih_p);
  pack_w_kernel<<<384, 256, 0, stream>>>(w_hh, whh_p);

  for (int c = 0; c < G; c++){
    int t0 = c * Tc;
    conv_gelu_kernel<<<512 * Tc, 256, 0, stream>>>(frames, conv_w, conv_b, feat_c, t0, Tc);
    gates_gemm_kernel<<<8 * Tc, 256, 0, stream>>>(feat_c, wih_p, b_ih, gates_c);
    scan_init_kernel<<<64, 256, 0, stream>>>(flags, h_glob, c == 0);
    gru_scan_kernel<<<256, 256, 0, stream>>>(gates_c, whh_p, b_hh, h_glob, h_state,
                                             flags, outs_c, Tc, t0);
    deconv_kernel<<<512 * Tc, 256, 0, stream>>>(outs_c, deconv_w, deconv_b, frames, out, t0, Tc);
  }
}

// Round 4
// 1336.759 us; speedup vs baseline: 6.4329x; 5.0718x over previous
//
#include <hip/hip_runtime.h>
#include <cstdint>

typedef float f32x4 __attribute__((ext_vector_type(4)));
typedef __bf16 bf16x8 __attribute__((ext_vector_type(8)));
typedef unsigned short us8 __attribute__((ext_vector_type(8)));

#define T2 126

__device__ __forceinline__ unsigned short f2bf(float x){
  union { float f; uint32_t u; } v; v.f = x;
  return (unsigned short)((v.u + 0x7fffu + ((v.u >> 16) & 1u)) >> 16);
}
__device__ __forceinline__ float bf2f(unsigned short h){
  union { uint32_t u; float f; } v; v.u = ((uint32_t)h) << 16; return v.f;
}
__device__ __forceinline__ f32x4 mfma_bf16(us8 a, us8 b, f32x4 c){
  return __builtin_amdgcn_mfma_f32_16x16x32_bf16(
      __builtin_bit_cast(bf16x8, a), __builtin_bit_cast(bf16x8, b), c, 0, 0, 0);
}
__device__ __forceinline__ float sigm(float x){ return 1.0f / (1.0f + __expf(-x)); }

// XOR-swizzled LDS address for a [rows][512] bf16 tile, 8-short chunks.
#define HSWZ(row, chunk) ((row) * 512 + ((((chunk) ^ ((row) & 7))) << 3))

// ---------------------------------------------------------------------------
// Pack (1536,512) fp32 weights -> bf16 MFMA B-fragments.
// Tile (jt,kt): lane l elem e holds W[16jt+(l&15)][32kt+8*(l>>4)+e]
// at dst[(jt*16+kt)*512 + l*8 + e]
// ---------------------------------------------------------------------------
__global__ void __launch_bounds__(256) pack_w_kernel(const float* __restrict__ w,
                                                     unsigned short* __restrict__ dst){
  int tid = blockIdx.x * 256 + threadIdx.x;     // 0..98303
  int l = tid & 63;
  int tile = tid >> 6;                          // jt*16 + kt
  int kt = tile & 15, jt = tile >> 4;
  int row = jt * 16 + (l & 15);
  int col = kt * 32 + (l >> 4) * 8;
  const float* s = w + (size_t)row * 512 + col;
  unsigned short o[8];
  #pragma unroll
  for (int e = 0; e < 8; e++) o[e] = f2bf(s[e]);
  *(us8*)(dst + (size_t)tid * 8) = *(const us8*)o;
}

// ---------------------------------------------------------------------------
// Patchify conv + bias + exact GELU -> feat_c bf16 (chunk-local)
// ---------------------------------------------------------------------------
__global__ void __launch_bounds__(256) conv_gelu_kernel(const float* __restrict__ frames,
                                                        const float* __restrict__ cw,
                                                        const float* __restrict__ cb,
                                                        unsigned short* __restrict__ feat_c,
                                                        int t0, int Tc){
  __shared__ float im[512];
  __shared__ float wl[1024];
  int n = blockIdx.x;
  int b = n / Tc, tl = n - b * Tc;
  int t = t0 + tl;
  const float* fr = frames + ((size_t)b * 128 + t) * 256;
  int tid = threadIdx.x;
  ((float2*)im)[tid] = ((const float2*)fr)[tid];
  #pragma unroll
  for (int i = 0; i < 4; i++) wl[tid + 256 * i] = cw[tid + 256 * i];
  __syncthreads();
  #pragma unroll
  for (int half = 0; half < 2; half++){
    int oi = tid + half * 256;
    int o = oi >> 4, ii = (oi >> 2) & 3, jj = oi & 3;
    const float* wc = &wl[o * 32];
    float s = cb[o];
    #pragma unroll
    for (int p = 0; p < 4; p++)
      #pragma unroll
      for (int q = 0; q < 4; q++){
        int pix = (ii * 4 + p) * 16 + jj * 4 + q;
        s += im[256 + pix] * wc[p * 4 + q] + im[pix] * wc[16 + p * 4 + q];
      }
    float g = 0.5f * s * (1.0f + erff(s * 0.70710678118654752f));
    feat_c[(size_t)n * 512 + oi] = f2bf(g);
  }
}

// ---------------------------------------------------------------------------
// gates_c = feat_c @ w_ih^T + b_ih -> bf16 (n_c, 1536)
// ---------------------------------------------------------------------------
__global__ void __launch_bounds__(256) gates_gemm_kernel(const unsigned short* __restrict__ feat_c,
                                                         const unsigned short* __restrict__ wih_p,
                                                         const float* __restrict__ b_ih,
                                                         unsigned short* __restrict__ gates_c){
  __shared__ unsigned short alds[64 * 512];
  int tid = threadIdx.x;
  int m0 = blockIdx.x * 64;
  #pragma unroll
  for (int it = 0; it < 16; it++){
    int cid = tid + 256 * it;
    int row = cid >> 6, ch = cid & 63;
    uint4 v = *(const uint4*)(feat_c + (size_t)(m0 + row) * 512 + ch * 8);
    *(uint4*)&alds[HSWZ(row, ch)] = v;
  }
  __syncthreads();
  int l = tid & 63, w = tid >> 6;
  int lr = l & 15, lh = l >> 4;
  for (int jg = 0; jg < 6; jg++){
    int jt0 = w * 24 + jg * 4;
    f32x4 acc[4][4];
    #pragma unroll
    for (int mt = 0; mt < 4; mt++)
      #pragma unroll
      for (int jj = 0; jj < 4; jj++) acc[mt][jj] = (f32x4){0.f,0.f,0.f,0.f};
    #pragma unroll
    for (int kt = 0; kt < 16; kt++){
      us8 a[4], bf[4];
      #pragma unroll
      for (int mt = 0; mt < 4; mt++){
        int row = mt * 16 + lr;
        int ch = kt * 4 + lh;
        a[mt] = *(const us8*)&alds[HSWZ(row, ch)];
      }
      #pragma unroll
      for (int jj = 0; jj < 4; jj++)
        bf[jj] = *(const us8*)(wih_p + ((size_t)((jt0 + jj) * 16 + kt) * 512 + l * 8));
      #pragma unroll
      for (int mt = 0; mt < 4; mt++)
        #pragma unroll
        for (int jj = 0; jj < 4; jj++)
          acc[mt][jj] = mfma_bf16(a[mt], bf[jj], acc[mt][jj]);
    }
    #pragma unroll
    for (int jj = 0; jj < 4; jj++){
      int j = (jt0 + jj) * 16 + lr;
      float bias = b_ih[j];
      #pragma unroll
      for (int mt = 0; mt < 4; mt++)
        #pragma unroll
        for (int r = 0; r < 4; r++){
          int m = m0 + mt * 16 + lh * 4 + r;
          gates_c[(size_t)m * 1536 + j] = f2bf(acc[mt][jj][r] + bias);
        }
    }
  }
}

// ---------------------------------------------------------------------------
// Reset flags each scan launch; zero h_glob on the first chunk.
// ---------------------------------------------------------------------------
__global__ void __launch_bounds__(256) scan_init_kernel(unsigned int* __restrict__ flags,
                                                        unsigned short* __restrict__ h_glob,
                                                        int first){
  int tid = blockIdx.x * 256 + threadIdx.x;
  if (tid < 256) flags[tid] = 0;
  if (first){
    for (int i = tid; i < 2 * 512 * 512; i += gridDim.x * 256)
      h_glob[i] = 0;
  }
}

// ---------------------------------------------------------------------------
// Weight-stationary persistent GRU scan — fence-free.
// Grid = 256 blocks = 16 batch-groups (32 rows) x 16 hidden-slices (32 cols).
// w_hh fragments pinned in VGPRs via volatile loads (non-rematerializable).
// Cross-block h/flags use relaxed agent-scope atomics (coherent at LLC, no
// L2 flush). Ordering: inline-asm vmcnt(0) drain before flag publish;
// reader issues h loads only after observing the flag. Monotone flags +
// double-buffered h_glob => no WAR hazard.
// ---------------------------------------------------------------------------
__global__ void __launch_bounds__(256, 1) gru_scan_kernel(
    const unsigned short* __restrict__ gates_c,
    const unsigned short* __restrict__ whh_p,
    const float* __restrict__ b_hh,
    unsigned short* __restrict__ h_glob,   // [2][512][512] bf16
    float* __restrict__ h_state,           // [512][512] fp32 chunk carry
    unsigned int* __restrict__ flags,      // [16 groups][16 slices]
    unsigned short* __restrict__ outs_c,
    int Tc, int t0){
  __shared__ unsigned short hlds[32 * 512];
  const int tid = threadIdx.x;
  const int B = blockIdx.x;
  const int grp = (B & 7) * 2 + ((B >> 3) >> 4);   // 0..15, same-XCD cluster
  const int slc = (B >> 3) & 15;                   // 0..15
  const int l = tid & 63;
  const int w = tid >> 6;                          // wave 0..3
  const int mt = w & 1, jg = w >> 1;
  const int lr = l & 15, lh = l >> 4;
  const int j = slc * 32 + jg * 16 + lr;           // hidden col
  const int rowbase = grp * 32 + mt * 16 + lh * 4; // + r = batch row

  // persistent weight fragments, pinned via volatile loads
  us8 wr[16], wz[16], wn[16];
  {
    const int jtR = slc * 2 + jg;
    #pragma unroll
    for (int kt = 0; kt < 16; kt++){
      wr[kt] = *(volatile const us8*)(whh_p + ((size_t)((jtR      ) * 16 + kt) * 512 + l * 8));
      wz[kt] = *(volatile const us8*)(whh_p + ((size_t)((jtR + 32) * 16 + kt) * 512 + l * 8));
      wn[kt] = *(volatile const us8*)(whh_p + ((size_t)((jtR + 64) * 16 + kt) * 512 + l * 8));
    }
  }
  const float bhr = b_hh[j], bhz = b_hh[512 + j], bhn = b_hh[1024 + j];
  float hprev[4];
  if (t0 == 0){
    hprev[0] = hprev[1] = hprev[2] = hprev[3] = 0.0f;
  } else {
    #pragma unroll
    for (int r = 0; r < 4; r++) hprev[r] = h_state[(size_t)(rowbase + r) * 512 + j];
  }
  unsigned int* gflag = flags + grp * 16;

  for (int tl = 0; tl < Tc; tl++){
    const int s = t0 + tl;
    const unsigned short* hbuf = h_glob + (size_t)(s & 1) * (512 * 512);
    unsigned short* hnext = h_glob + (size_t)((s + 1) & 1) * (512 * 512);
    // prefetch gx for this step (normal loads; overlaps the spin)
    float gxr[4], gxz[4], gxn[4];
    #pragma unroll
    for (int r = 0; r < 4; r++){
      size_t gb = ((size_t)(rowbase + r) * Tc + tl) * 1536;
      gxr[r] = bf2f(gates_c[gb + j]);
      gxz[r] = bf2f(gates_c[gb + 512 + j]);
      gxn[r] = bf2f(gates_c[gb + 1024 + j]);
    }
    // wait until every slice of this group has published h(s)
    if (tl > 0){
      if (tid < 16){
        while ((int)__hip_atomic_load(&gflag[tid], __ATOMIC_RELAXED,
                                      __HIP_MEMORY_SCOPE_AGENT) < tl)
          __builtin_amdgcn_s_sleep(2);
      }
    }
    __syncthreads();                 // all threads past the wait; WAR for hlds
    // stage h(s) rows [grp*32, grp*32+32) into LDS via coherent u64 loads
    #pragma unroll
    for (int it = 0; it < 8; it++){
      int cid = tid + 256 * it;
      int row = cid >> 6, ch = cid & 63;
      unsigned long long* src = (unsigned long long*)(hbuf + (size_t)(grp * 32 + row) * 512 + ch * 8);
      unsigned long long lo = __hip_atomic_load(src,     __ATOMIC_RELAXED, __HIP_MEMORY_SCOPE_AGENT);
      unsigned long long hi = __hip_atomic_load(src + 1, __ATOMIC_RELAXED, __HIP_MEMORY_SCOPE_AGENT);
      union { unsigned long long q[2]; us8 v; } u;
      u.q[0] = lo; u.q[1] = hi;
      *(us8*)&hlds[HSWZ(row, ch)] = u.v;
    }
    __syncthreads();
    f32x4 aR = {0.f,0.f,0.f,0.f}, aZ = {0.f,0.f,0.f,0.f}, aN = {0.f,0.f,0.f,0.f};
    #pragma unroll
    for (int kt = 0; kt < 16; kt++){
      us8 a = *(const us8*)&hlds[HSWZ(mt * 16 + lr, kt * 4 + lh)];
      aR = mfma_bf16(a, wr[kt], aR);
      aZ = mfma_bf16(a, wz[kt], aZ);
      aN = mfma_bf16(a, wn[kt], aN);
    }
    #pragma unroll
    for (int r = 0; r < 4; r++){
      float rr = sigm(gxr[r] + aR[r] + bhr);
      float zz = sigm(gxz[r] + aZ[r] + bhz);
      float nn = tanhf(gxn[r] + rr * (aN[r] + bhn));
      float hv = (1.0f - zz) * nn + zz * hprev[r];
      hprev[r] = hv;
      unsigned short hb = f2bf(hv);
      __hip_atomic_store(&hnext[(size_t)(rowbase + r) * 512 + j], hb,
                         __ATOMIC_RELAXED, __HIP_MEMORY_SCOPE_AGENT);
      outs_c[((size_t)(rowbase + r) * Tc + tl) * 512 + j] = hb;
    }
    asm volatile("s_waitcnt vmcnt(0)" ::: "memory");  // h stores at coherence point
    __syncthreads();                 // all waves of this block done
    if (tid == 0)
      __hip_atomic_store(&gflag[slc], (unsigned)(tl + 1), __ATOMIC_RELAXED,
                         __HIP_MEMORY_SCOPE_AGENT);
  }
  // fp32 carry for next chunk
  #pragma unroll
  for (int r = 0; r < 4; r++)
    h_state[(size_t)(rowbase + r) * 512 + j] = hprev[r];
}

// ---------------------------------------------------------------------------
// Deconv + tanh + residual + clip -> fp32 output
// ---------------------------------------------------------------------------
__global__ void __launch_bounds__(256) deconv_kernel(const unsigned short* __restrict__ outs_c,
                                                     const float* __restrict__ dw,
                                                     const float* __restrict__ db,
                                                     const float* __restrict__ frames,
                                                     float* __restrict__ out,
                                                     int t0, int Tc){
  __shared__ float wl[512];
  __shared__ float dv[512];
  int n = blockIdx.x;
  int b = n / Tc, tl = n - b * Tc;
  int t = t0 + tl;
  int tid = threadIdx.x;
  wl[tid] = dw[tid]; wl[tid + 256] = dw[tid + 256];
  dv[tid] = bf2f(outs_c[(size_t)n * 512 + tid]);
  dv[tid + 256] = bf2f(outs_c[(size_t)n * 512 + tid + 256]);
  __syncthreads();
  int row = tid >> 4, col = tid & 15;
  int ii = row >> 2, p = row & 3, jj = col >> 2, q = col & 3;
  float s = db[0];
  #pragma unroll
  for (int c = 0; c < 32; c++)
    s += dv[c * 16 + ii * 4 + jj] * wl[c * 16 + p * 4 + q];
  float d = tanhf(s);
  float cv = frames[((size_t)b * 128 + (t + 1)) * 256 + tid];
  float r = cv + d;
  out[((size_t)b * T2 + t) * 256 + tid] = fminf(fmaxf(r, 0.0f), 1.0f);
}

extern "C" void kernel_launch(void* const* d_in, const int* in_sizes, int n_in,
                              void* d_out, int out_size, void* d_ws, size_t ws_size,
                              hipStream_t stream) {
  const float* frames   = (const float*)d_in[0];
  const float* conv_w   = (const float*)d_in[1];
  const float* conv_b   = (const float*)d_in[2];
  const float* w_ih     = (const float*)d_in[3];
  const float* w_hh     = (const float*)d_in[4];
  const float* b_ih     = (const float*)d_in[5];
  const float* b_hh     = (const float*)d_in[6];
  const float* deconv_w = (const float*)d_in[7];
  const float* deconv_b = (const float*)d_in[8];
  float* out = (float*)d_out;
  char* ws = (char*)d_ws;

  // fixed region: wih_p 1.5M | whh_p 1.5M | h_state 1M | h_glob 1M | flags 4K
  unsigned short* wih_p   = (unsigned short*)(ws);
  unsigned short* whh_p   = (unsigned short*)(ws + 1572864LL);
  float*          h_state = (float*)         (ws + 3145728LL);
  unsigned short* h_glob  = (unsigned short*)(ws + 4194304LL);
  unsigned int*   flags   = (unsigned int*)  (ws + 5242880LL);
  char*           chunkws = ws + 5246976LL;

  // chunked region: feat 0.5M/t + gates 1.5M/t + outs 0.5M/t
  static const int divs[12] = {126, 63, 42, 21, 18, 14, 9, 7, 6, 3, 2, 1};
  int Tc = 1;
  for (int i = 0; i < 12; i++){
    long long need = 5246976LL + 2621440LL * divs[i];
    if (need <= (long long)ws_size){ Tc = divs[i]; break; }
  }
  int G = T2 / Tc;

  unsigned short* feat_c  = (unsigned short*)(chunkws);
  unsigned short* gates_c = (unsigned short*)(chunkws +  524288LL * Tc);
  unsigned short* outs_c  = (unsigned short*)(chunkws + 2097152LL * Tc);

  pack_w_kernel<<<384, 256, 0, stream>>>(w_ih, wih_p);
  pack_w_kernel<<<384, 256, 0, stream>>>(w_hh, whh_p);

  for (int c = 0; c < G; c++){
    int t0 = c * Tc;
    conv_gelu_kernel<<<512 * Tc, 256, 0, stream>>>(frames, conv_w, conv_b, feat_c, t0, Tc);
    gates_gemm_kernel<<<8 * Tc, 256, 0, stream>>>(feat_c, wih_p, b_ih, gates_c);
    scan_init_kernel<<<64, 256, 0, stream>>>(flags, h_glob, c == 0);
    gru_scan_kernel<<<256, 256, 0, stream>>>(gates_c, whh_p, b_hh, h_glob, h_state,
                                             flags, outs_c, Tc, t0);
    deconv_kernel<<<512 * Tc, 256, 0, stream>>>(outs_c, deconv_w, deconv_b, frames, out, t0, Tc);
  }
}